// Round 7
// baseline (235.005 us; speedup 1.0000x reference)
//
#include <hip/hip_runtime.h>
#include <hip/hip_fp16.h>

#define WAVE 64

constexpr int D_IN = 128;
constexpr int F1 = 64;
constexpr int F2 = 128;
constexpr int NG = 64;
constexpr float NEG = 0.2f;
constexpr int NBLK1 = 512;       // level-1 binning blocks

using f16x8 = __attribute__((ext_vector_type(8))) _Float16;
using f32x4 = __attribute__((ext_vector_type(4))) float;

__device__ __forceinline__ float lrelu(float x){ return x > 0.f ? x : NEG * x; }

// ================= CSR build: two-level LDS-binned counting sort =================
__global__ void k_hist(const int* __restrict__ src, const int* __restrict__ dst,
                       int E, int N, int NB, int chunk, int* __restrict__ cnt1){
  __shared__ int hist[256];
  int b = blockIdx.x;
  for (int t = threadIdx.x; t < NB; t += blockDim.x) hist[t] = 0;
  __syncthreads();
  int Et = E + N;
  int s0 = b * chunk, s1 = min(s0 + chunk, Et);
  for (int i = s0 + (int)threadIdx.x; i < s1; i += (int)blockDim.x){
    int d = (i < E) ? dst[i] : (i - E);
    atomicAdd(&hist[d >> 8], 1);
  }
  __syncthreads();
  for (int t = threadIdx.x; t < NB; t += blockDim.x) cnt1[t * NBLK1 + b] = hist[t];
}

__global__ void k_colscan(int* __restrict__ cnt1, int* __restrict__ btot){
  __shared__ int lds[256];
  int b = blockIdx.x;
  int t = threadIdx.x;
  int v0 = cnt1[b * NBLK1 + 2 * t], v1 = cnt1[b * NBLK1 + 2 * t + 1];
  int p = v0 + v1;
  lds[t] = p; __syncthreads();
  #pragma unroll
  for (int s = 1; s < 256; s <<= 1){
    int u = (t >= s) ? lds[t - s] : 0;
    __syncthreads(); lds[t] += u; __syncthreads();
  }
  int epre = lds[t] - p;
  cnt1[b * NBLK1 + 2 * t] = epre;
  cnt1[b * NBLK1 + 2 * t + 1] = epre + v0;
  if (t == 255) btot[b] = lds[255];
}

__global__ void k_bucketscan(const int* __restrict__ btot, int NB, int Et,
                             int* __restrict__ bbase, int* __restrict__ off, int N){
  __shared__ int lds[256];
  int t = threadIdx.x;
  int v = (t < NB) ? btot[t] : 0;
  lds[t] = v; __syncthreads();
  #pragma unroll
  for (int s = 1; s < 256; s <<= 1){
    int u = (t >= s) ? lds[t - s] : 0;
    __syncthreads(); lds[t] += u; __syncthreads();
  }
  if (t < NB) bbase[t] = lds[t] - v;
  if (t == 0){ bbase[NB] = Et; off[N] = Et; }
}

__global__ void k_scatter1(const int* __restrict__ src, const int* __restrict__ dst,
                           int E, int N, int NB, int chunk,
                           const int* __restrict__ cnt1, const int* __restrict__ bbase,
                           int* __restrict__ tmp){
  __shared__ int cur[256];
  int b = blockIdx.x;
  for (int t = threadIdx.x; t < NB; t += blockDim.x) cur[t] = bbase[t] + cnt1[t * NBLK1 + b];
  __syncthreads();
  int Et = E + N;
  int s0 = b * chunk, s1 = min(s0 + chunk, Et);
  for (int i = s0 + (int)threadIdx.x; i < s1; i += (int)blockDim.x){
    int s, d;
    if (i < E){ s = src[i]; d = dst[i]; } else { s = d = i - E; }
    int bk = d >> 8;
    int p = atomicAdd(&cur[bk], 1);
    tmp[p] = (s << 8) | (d & 255);
  }
}

__global__ void k_sort2(const int* __restrict__ tmp, const int* __restrict__ bbase,
                        int N, int* __restrict__ off, int* __restrict__ csr_src,
                        int* __restrict__ dst_arr){
  __shared__ int hist[256];
  __shared__ int pre[256];
  int b = blockIdx.x;
  int t = threadIdx.x;
  hist[t] = 0;
  __syncthreads();
  int g0 = bbase[b], g1 = bbase[b + 1];
  for (int i = g0 + t; i < g1; i += 256) atomicAdd(&hist[tmp[i] & 255], 1);
  __syncthreads();
  int v = hist[t];
  pre[t] = v; __syncthreads();
  #pragma unroll
  for (int s = 1; s < 256; s <<= 1){
    int u = (t >= s) ? pre[t - s] : 0;
    __syncthreads(); pre[t] += u; __syncthreads();
  }
  int ex = pre[t] - v;
  int node = (b << 8) + t;
  if (node < N) off[node] = g0 + ex;
  hist[t] = ex;
  __syncthreads();
  for (int i = g0 + t; i < g1; i += 256){
    int e = tmp[i];
    int p = g0 + atomicAdd(&hist[e & 255], 1);
    csr_src[p] = e >> 8;
    dst_arr[p] = (b << 8) | (e & 255);
  }
}

// ---------------- per-edge softmax weights (coalesced, lane-parallel) ----------------
__global__ void k_weight(const int* __restrict__ csr_src, const int* __restrict__ dst_arr,
                         const float* __restrict__ as_, const float* __restrict__ ad_,
                         float* __restrict__ we, int Et){
  int i = blockIdx.x * blockDim.x + threadIdx.x;
  int stride = gridDim.x * blockDim.x;
  for (; i < Et; i += stride)
    we[i] = __expf(lrelu(as_[csr_src[i]] + ad_[dst_arr[i]]));
}

// ============ MFMA GEMM: Ch[M,FO](fp16) = A[M,FI] @ W[FI,FO]; plus as/ad dots ============
template<int FI, int FO, bool AF32>
__global__ void k_gemm_mfma(const void* __restrict__ Av, const float* __restrict__ W,
                            const float* __restrict__ avs, const float* __restrict__ avd,
                            __half* __restrict__ Ch, float* __restrict__ as_, float* __restrict__ ad_,
                            int M){
  constexpr int NT = FO / 16;
  constexpr int KT = FI / 32;
  constexpr int MT = 2;
  __shared__ _Float16 blds[NT * KT * 64 * 8];

  int tid = threadIdx.x;
  for (int fl = tid; fl < NT * KT * 64; fl += 256){
    int l = fl & 63, kt = (fl >> 6) % KT, nt = fl / (64 * KT);
    int n = nt * 16 + (l & 15), kb = kt * 32 + (l >> 4) * 8;
    f16x8 v;
    #pragma unroll
    for (int i = 0; i < 8; ++i) v[i] = (_Float16)W[(size_t)(kb + i) * FO + n];
    *(f16x8*)&blds[(size_t)fl * 8] = v;
  }
  __syncthreads();

  int lane = tid & 63, wave = tid >> 6;
  int rbase = lane & 15, kgrp = lane >> 4;
  int r0 = blockIdx.x * (MT * 16 * 4) + wave * (MT * 16);

  f32x4 c[MT][NT];
  #pragma unroll
  for (int mt = 0; mt < MT; ++mt)
    #pragma unroll
    for (int nt = 0; nt < NT; ++nt)
      c[mt][nt] = (f32x4){0.f, 0.f, 0.f, 0.f};

  for (int kt = 0; kt < KT; ++kt){
    f16x8 a[MT];
    #pragma unroll
    for (int mt = 0; mt < MT; ++mt){
      int arow = min(r0 + mt * 16 + rbase, M - 1);
      if (AF32){
        const float* ap = (const float*)Av + (size_t)arow * FI + kt * 32 + kgrp * 8;
        float4 p0 = *(const float4*)ap;
        float4 p1 = *(const float4*)(ap + 4);
        a[mt][0] = (_Float16)p0.x; a[mt][1] = (_Float16)p0.y;
        a[mt][2] = (_Float16)p0.z; a[mt][3] = (_Float16)p0.w;
        a[mt][4] = (_Float16)p1.x; a[mt][5] = (_Float16)p1.y;
        a[mt][6] = (_Float16)p1.z; a[mt][7] = (_Float16)p1.w;
      } else {
        const __half* ap = (const __half*)Av + (size_t)arow * FI + kt * 32 + kgrp * 8;
        a[mt] = *(const f16x8*)ap;
      }
    }
    #pragma unroll
    for (int nt = 0; nt < NT; ++nt){
      f16x8 b = *(f16x8*)&blds[(size_t)((nt * KT + kt) * 64 + lane) * 8];
      #pragma unroll
      for (int mt = 0; mt < MT; ++mt)
        c[mt][nt] = __builtin_amdgcn_mfma_f32_16x16x32_f16(a[mt], b, c[mt][nt], 0, 0, 0);
    }
  }

  float avs_v[NT], avd_v[NT];
  #pragma unroll
  for (int nt = 0; nt < NT; ++nt){
    avs_v[nt] = avs[nt * 16 + rbase];
    avd_v[nt] = avd[nt * 16 + rbase];
  }
  #pragma unroll
  for (int mt = 0; mt < MT; ++mt){
    #pragma unroll
    for (int i = 0; i < 4; ++i){
      int grow = r0 + mt * 16 + kgrp * 4 + i;
      bool ok = grow < M;
      float s1 = 0.f, s2 = 0.f;
      #pragma unroll
      for (int nt = 0; nt < NT; ++nt){
        float d = c[mt][nt][i];
        if (ok) Ch[(size_t)grow * FO + nt * 16 + rbase] = __float2half(d);
        s1 += d * avs_v[nt];
        s2 += d * avd_v[nt];
      }
      #pragma unroll
      for (int msk = 1; msk <= 8; msk <<= 1){
        s1 += __shfl_xor(s1, msk);
        s2 += __shfl_xor(s2, msk);
      }
      if (ok && rbase == 0){ as_[grow] = s1; ad_[grow] = s2; }
    }
  }
}

// ---------------- aggregation: scalarized wave-per-node, precomputed weights ----------------
// F=64: lane owns col=lane. F=128: lane owns cols {2*lane, 2*lane+1}.
template<int F>
__global__ void k_node(const int* __restrict__ off, const int* __restrict__ csr_src,
                       const float* __restrict__ we, const __half* __restrict__ h,
                       const float* __restrict__ bias, __half* __restrict__ outh, int N){
  constexpr int CPL = F / WAVE;
  int lane = threadIdx.x & (WAVE - 1);
  int wid = (int)((blockIdx.x * blockDim.x + threadIdx.x) >> 6);
  int node = __builtin_amdgcn_readfirstlane(wid);
  if (node >= N) return;
  int o0 = off[node], o1 = off[node + 1];
  const __half* hb = h + ((CPL == 1) ? lane : 2 * lane);
  float acc0 = 0.f, acc1 = 0.f, wsum = 0.f;
  int j = o0;
  for (; j + 8 <= o1; j += 8){
    int s[8]; float w[8];
    #pragma unroll
    for (int u = 0; u < 8; ++u){ s[u] = csr_src[j + u]; w[u] = we[j + u]; }
    #pragma unroll
    for (int u = 0; u < 8; ++u){
      if (CPL == 1){
        float r = __half2float(hb[(size_t)s[u] * F]);
        acc0 += w[u] * r;
      } else {
        float2 r = __half22float2(*(const __half2*)(hb + (size_t)s[u] * F));
        acc0 += w[u] * r.x;
        acc1 += w[u] * r.y;
      }
      wsum += w[u];
    }
  }
  for (; j < o1; ++j){
    int s = csr_src[j];
    float w = we[j];
    if (CPL == 1){
      acc0 += w * __half2float(hb[(size_t)s * F]);
    } else {
      float2 r = __half22float2(*(const __half2*)(hb + (size_t)s * F));
      acc0 += w * r.x;
      acc1 += w * r.y;
    }
    wsum += w;
  }
  float inv = 1.f / (wsum + 1e-16f);
  if (CPL == 1){
    float v = fmaxf(acc0 * inv + bias[lane], 0.f);
    outh[(size_t)node * F + lane] = __float2half(v);
  } else {
    float v0 = fmaxf(acc0 * inv + bias[2 * lane], 0.f);
    float v1 = fmaxf(acc1 * inv + bias[2 * lane + 1], 0.f);
    *(__half2*)(outh + (size_t)node * F + 2 * lane) = __floats2half2_rn(v0, v1);
  }
}

// ---------------- pooling (batch sorted): strip reduction, few atomics ----------------
__global__ void k_pool(const __half* __restrict__ h, const int* __restrict__ batch,
                       float* __restrict__ pool, int* __restrict__ cnt, int N, int strip){
  int f = threadIdx.x;  // 0..127
  int n0 = blockIdx.x * strip;
  if (n0 >= N) return;
  int n1 = min(n0 + strip, N);
  int g = batch[n0];
  float acc = 0.f;
  int c = 0;
  for (int n = n0; n < n1; ++n){
    int gn = batch[n];
    if (gn != g){
      atomicAdd(&pool[g * F2 + f], acc);
      if (f == 0) atomicAdd(&cnt[g], c);
      acc = 0.f; c = 0; g = gn;
    }
    acc += __half2float(h[(size_t)n * F2 + f]);
    c++;
  }
  atomicAdd(&pool[g * F2 + f], acc);
  if (f == 0) atomicAdd(&cnt[g], c);
}

// ---------------- final FC ----------------
__global__ void k_fc(const float* __restrict__ pool, const int* __restrict__ cnt,
                     const float* __restrict__ Wfc, const float* __restrict__ bfc,
                     float* __restrict__ out){
  int g = blockIdx.x, o = threadIdx.x;  // 64 x 64
  __shared__ float p[F2];
  float invc = 1.f / fmaxf((float)cnt[g], 1.f);
  for (int k = threadIdx.x; k < F2; k += 64) p[k] = pool[g * F2 + k] * invc;
  __syncthreads();
  float acc = bfc[o];
  for (int k = 0; k < F2; ++k) acc += p[k] * Wfc[k * 64 + o];
  out[g * 64 + o] = acc;
}

extern "C" void kernel_launch(void* const* d_in, const int* in_sizes, int n_in,
                              void* d_out, int out_size, void* d_ws, size_t ws_size,
                              hipStream_t stream){
  const float* x    = (const float*)d_in[0];
  const int*   edge = (const int*)d_in[1];
  const int*   batch= (const int*)d_in[2];
  const float* W1   = (const float*)d_in[3];
  const float* av_s1= (const float*)d_in[4];
  const float* av_d1= (const float*)d_in[5];
  const float* b1   = (const float*)d_in[6];
  const float* W2   = (const float*)d_in[7];
  const float* av_s2= (const float*)d_in[8];
  const float* av_d2= (const float*)d_in[9];
  const float* b2   = (const float*)d_in[10];
  const float* Wfc  = (const float*)d_in[11];
  const float* bfc  = (const float*)d_in[12];
  float* out = (float*)d_out;

  const int N  = in_sizes[2];
  const int E  = in_sizes[1] / 2;
  const int Et = E + N;
  const int NB = (N + 255) >> 8;
  const int* src = edge;
  const int* dst = edge + E;

  char* p = (char*)d_ws;
  auto alloc = [&](size_t bytes)->void*{
    void* r = (void*)p;
    p += (bytes + 255) & ~(size_t)255;
    return r;
  };
  __half* h1  = (__half*)alloc((size_t)N * F1 * 2);
  __half* h1r = (__half*)alloc((size_t)N * F1 * 2);
  __half* h2  = (__half*)alloc((size_t)N * F2 * 2);
  __half* h2r = (__half*)alloc((size_t)N * F2 * 2);
  float* as1  = (float*)alloc((size_t)N * 4);
  float* ad1  = (float*)alloc((size_t)N * 4);
  float* as2  = (float*)alloc((size_t)N * 4);
  float* ad2  = (float*)alloc((size_t)N * 4);
  float* pool = (float*)alloc((size_t)NG * F2 * 4);
  float* we   = (float*)alloc((size_t)Et * 4);
  int* off    = (int*)alloc((size_t)(N + 1) * 4);
  int* csr_src= (int*)alloc((size_t)Et * 4);
  int* dst_arr= (int*)alloc((size_t)Et * 4);
  int* tmp    = (int*)alloc((size_t)Et * 4);
  int* cnt1   = (int*)alloc((size_t)256 * NBLK1 * 4);
  int* btot   = (int*)alloc((size_t)256 * 4);
  int* bbase  = (int*)alloc((size_t)257 * 4);
  int* cnt    = (int*)alloc((size_t)NG * 4);

  hipMemsetAsync(pool, 0, (size_t)NG * F2 * 4, stream);
  hipMemsetAsync(cnt, 0, (size_t)NG * 4, stream);

  // CSR build (no global atomics)
  int chunk = (Et + NBLK1 - 1) / NBLK1;
  k_hist<<<NBLK1, 256, 0, stream>>>(src, dst, E, N, NB, chunk, cnt1);
  k_colscan<<<NB, 256, 0, stream>>>(cnt1, btot);
  k_bucketscan<<<1, 256, 0, stream>>>(btot, NB, Et, bbase, off, N);
  k_scatter1<<<NBLK1, 256, 0, stream>>>(src, dst, E, N, NB, chunk, cnt1, bbase, tmp);
  k_sort2<<<NB, 256, 0, stream>>>(tmp, bbase, N, off, csr_src, dst_arr);

  int gemm_blocks = (N + 127) / 128;
  int node_blocks = (N + 3) / 4;   // 4 waves (nodes) per 256-thread block
  int wblocks = 2048;

  // layer 1
  k_gemm_mfma<D_IN, F1, true><<<gemm_blocks, 256, 0, stream>>>(x, W1, av_s1, av_d1,
                                                               h1, as1, ad1, N);
  k_weight<<<wblocks, 256, 0, stream>>>(csr_src, dst_arr, as1, ad1, we, Et);
  k_node<F1><<<node_blocks, 256, 0, stream>>>(off, csr_src, we, h1, b1, h1r, N);

  // layer 2
  k_gemm_mfma<F1, F2, false><<<gemm_blocks, 256, 0, stream>>>(h1r, W2, av_s2, av_d2,
                                                              h2, as2, ad2, N);
  k_weight<<<wblocks, 256, 0, stream>>>(csr_src, dst_arr, as2, ad2, we, Et);
  k_node<F2><<<node_blocks, 256, 0, stream>>>(off, csr_src, we, h2, b2, h2r, N);

  // pooling + FC
  int strip = 128;
  int pool_blocks = (N + strip - 1) / strip;
  k_pool<<<pool_blocks, F2, 0, stream>>>(h2r, batch, pool, cnt, N, strip);
  k_fc<<<NG, 64, 0, stream>>>(pool, cnt, Wfc, bfc, out);
}

// Round 8
// 231.177 us; speedup vs baseline: 1.0166x; 1.0166x over previous
//
#include <hip/hip_runtime.h>
#include <hip/hip_fp16.h>

#define WAVE 64

constexpr int D_IN = 128;
constexpr int F1 = 64;
constexpr int F2 = 128;
constexpr int NG = 64;
constexpr float NEG = 0.2f;
constexpr int NBLK1 = 512;       // level-1 binning blocks

using f16x8 = __attribute__((ext_vector_type(8))) _Float16;
using f32x4 = __attribute__((ext_vector_type(4))) float;

__device__ __forceinline__ float lrelu(float x){ return x > 0.f ? x : NEG * x; }

// ================= CSR build: two-level LDS-binned counting sort =================
__global__ void k_hist(const int* __restrict__ src, const int* __restrict__ dst,
                       int E, int N, int NB, int chunk, int* __restrict__ cnt1){
  __shared__ int hist[256];
  int b = blockIdx.x;
  for (int t = threadIdx.x; t < NB; t += blockDim.x) hist[t] = 0;
  __syncthreads();
  int Et = E + N;
  int s0 = b * chunk, s1 = min(s0 + chunk, Et);
  for (int i = s0 + (int)threadIdx.x; i < s1; i += (int)blockDim.x){
    int d = (i < E) ? dst[i] : (i - E);
    atomicAdd(&hist[d >> 8], 1);
  }
  __syncthreads();
  for (int t = threadIdx.x; t < NB; t += blockDim.x) cnt1[t * NBLK1 + b] = hist[t];
}

__global__ void k_colscan(int* __restrict__ cnt1, int* __restrict__ btot){
  __shared__ int lds[256];
  int b = blockIdx.x;
  int t = threadIdx.x;
  int v0 = cnt1[b * NBLK1 + 2 * t], v1 = cnt1[b * NBLK1 + 2 * t + 1];
  int p = v0 + v1;
  lds[t] = p; __syncthreads();
  #pragma unroll
  for (int s = 1; s < 256; s <<= 1){
    int u = (t >= s) ? lds[t - s] : 0;
    __syncthreads(); lds[t] += u; __syncthreads();
  }
  int epre = lds[t] - p;
  cnt1[b * NBLK1 + 2 * t] = epre;
  cnt1[b * NBLK1 + 2 * t + 1] = epre + v0;
  if (t == 255) btot[b] = lds[255];
}

__global__ void k_bucketscan(const int* __restrict__ btot, int NB, int Et,
                             int* __restrict__ bbase, int* __restrict__ off, int N){
  __shared__ int lds[256];
  int t = threadIdx.x;
  int v = (t < NB) ? btot[t] : 0;
  lds[t] = v; __syncthreads();
  #pragma unroll
  for (int s = 1; s < 256; s <<= 1){
    int u = (t >= s) ? lds[t - s] : 0;
    __syncthreads(); lds[t] += u; __syncthreads();
  }
  if (t < NB) bbase[t] = lds[t] - v;
  if (t == 0){ bbase[NB] = Et; off[N] = Et; }
}

__global__ void k_scatter1(const int* __restrict__ src, const int* __restrict__ dst,
                           int E, int N, int NB, int chunk,
                           const int* __restrict__ cnt1, const int* __restrict__ bbase,
                           int* __restrict__ tmp){
  __shared__ int cur[256];
  int b = blockIdx.x;
  for (int t = threadIdx.x; t < NB; t += blockDim.x) cur[t] = bbase[t] + cnt1[t * NBLK1 + b];
  __syncthreads();
  int Et = E + N;
  int s0 = b * chunk, s1 = min(s0 + chunk, Et);
  for (int i = s0 + (int)threadIdx.x; i < s1; i += (int)blockDim.x){
    int s, d;
    if (i < E){ s = src[i]; d = dst[i]; } else { s = d = i - E; }
    int bk = d >> 8;
    int p = atomicAdd(&cur[bk], 1);
    tmp[p] = (s << 8) | (d & 255);
  }
}

__global__ void k_sort2(const int* __restrict__ tmp, const int* __restrict__ bbase,
                        int N, int* __restrict__ off, int* __restrict__ csr_src,
                        int* __restrict__ dst_arr){
  __shared__ int hist[256];
  __shared__ int pre[256];
  int b = blockIdx.x;
  int t = threadIdx.x;
  hist[t] = 0;
  __syncthreads();
  int g0 = bbase[b], g1 = bbase[b + 1];
  for (int i = g0 + t; i < g1; i += 256) atomicAdd(&hist[tmp[i] & 255], 1);
  __syncthreads();
  int v = hist[t];
  pre[t] = v; __syncthreads();
  #pragma unroll
  for (int s = 1; s < 256; s <<= 1){
    int u = (t >= s) ? pre[t - s] : 0;
    __syncthreads(); pre[t] += u; __syncthreads();
  }
  int ex = pre[t] - v;
  int node = (b << 8) + t;
  if (node < N) off[node] = g0 + ex;
  hist[t] = ex;
  __syncthreads();
  for (int i = g0 + t; i < g1; i += 256){
    int e = tmp[i];
    int p = g0 + atomicAdd(&hist[e & 255], 1);
    csr_src[p] = e >> 8;
    dst_arr[p] = (b << 8) | (e & 255);
  }
}

// ---------------- per-edge softmax weights (coalesced, lane-parallel) ----------------
__global__ void k_weight(const int* __restrict__ csr_src, const int* __restrict__ dst_arr,
                         const float* __restrict__ as_, const float* __restrict__ ad_,
                         float* __restrict__ we, int Et){
  int i = blockIdx.x * blockDim.x + threadIdx.x;
  int stride = gridDim.x * blockDim.x;
  for (; i < Et; i += stride)
    we[i] = __expf(lrelu(as_[csr_src[i]] + ad_[dst_arr[i]]));
}

// ============ MFMA GEMM: Ch[M,FO](fp16) = A[M,FI] @ W[FI,FO]; plus as/ad dots ============
template<int FI, int FO, bool AF32>
__global__ void k_gemm_mfma(const void* __restrict__ Av, const float* __restrict__ W,
                            const float* __restrict__ avs, const float* __restrict__ avd,
                            __half* __restrict__ Ch, float* __restrict__ as_, float* __restrict__ ad_,
                            int M){
  constexpr int NT = FO / 16;
  constexpr int KT = FI / 32;
  constexpr int MT = 2;
  __shared__ _Float16 blds[NT * KT * 64 * 8];

  int tid = threadIdx.x;
  for (int fl = tid; fl < NT * KT * 64; fl += 256){
    int l = fl & 63, kt = (fl >> 6) % KT, nt = fl / (64 * KT);
    int n = nt * 16 + (l & 15), kb = kt * 32 + (l >> 4) * 8;
    f16x8 v;
    #pragma unroll
    for (int i = 0; i < 8; ++i) v[i] = (_Float16)W[(size_t)(kb + i) * FO + n];
    *(f16x8*)&blds[(size_t)fl * 8] = v;
  }
  __syncthreads();

  int lane = tid & 63, wave = tid >> 6;
  int rbase = lane & 15, kgrp = lane >> 4;
  int r0 = blockIdx.x * (MT * 16 * 4) + wave * (MT * 16);

  f32x4 c[MT][NT];
  #pragma unroll
  for (int mt = 0; mt < MT; ++mt)
    #pragma unroll
    for (int nt = 0; nt < NT; ++nt)
      c[mt][nt] = (f32x4){0.f, 0.f, 0.f, 0.f};

  for (int kt = 0; kt < KT; ++kt){
    f16x8 a[MT];
    #pragma unroll
    for (int mt = 0; mt < MT; ++mt){
      int arow = min(r0 + mt * 16 + rbase, M - 1);
      if (AF32){
        const float* ap = (const float*)Av + (size_t)arow * FI + kt * 32 + kgrp * 8;
        float4 p0 = *(const float4*)ap;
        float4 p1 = *(const float4*)(ap + 4);
        a[mt][0] = (_Float16)p0.x; a[mt][1] = (_Float16)p0.y;
        a[mt][2] = (_Float16)p0.z; a[mt][3] = (_Float16)p0.w;
        a[mt][4] = (_Float16)p1.x; a[mt][5] = (_Float16)p1.y;
        a[mt][6] = (_Float16)p1.z; a[mt][7] = (_Float16)p1.w;
      } else {
        const __half* ap = (const __half*)Av + (size_t)arow * FI + kt * 32 + kgrp * 8;
        a[mt] = *(const f16x8*)ap;
      }
    }
    #pragma unroll
    for (int nt = 0; nt < NT; ++nt){
      f16x8 b = *(f16x8*)&blds[(size_t)((nt * KT + kt) * 64 + lane) * 8];
      #pragma unroll
      for (int mt = 0; mt < MT; ++mt)
        c[mt][nt] = __builtin_amdgcn_mfma_f32_16x16x32_f16(a[mt], b, c[mt][nt], 0, 0, 0);
    }
  }

  float avs_v[NT], avd_v[NT];
  #pragma unroll
  for (int nt = 0; nt < NT; ++nt){
    avs_v[nt] = avs[nt * 16 + rbase];
    avd_v[nt] = avd[nt * 16 + rbase];
  }
  #pragma unroll
  for (int mt = 0; mt < MT; ++mt){
    #pragma unroll
    for (int i = 0; i < 4; ++i){
      int grow = r0 + mt * 16 + kgrp * 4 + i;
      bool ok = grow < M;
      float s1 = 0.f, s2 = 0.f;
      #pragma unroll
      for (int nt = 0; nt < NT; ++nt){
        float d = c[mt][nt][i];
        if (ok) Ch[(size_t)grow * FO + nt * 16 + rbase] = __float2half(d);
        s1 += d * avs_v[nt];
        s2 += d * avd_v[nt];
      }
      #pragma unroll
      for (int msk = 1; msk <= 8; msk <<= 1){
        s1 += __shfl_xor(s1, msk);
        s2 += __shfl_xor(s2, msk);
      }
      if (ok && rbase == 0){ as_[grow] = s1; ad_[grow] = s2; }
    }
  }
}

// ---------------- aggregation: grouped gather, 16B per lane, EPW edges per wave-instr --------
// LPR = F/8 lanes cover one row; EPW = 64/LPR edges processed per iteration.
// lane q = lane/LPR picks edge slot, cbase = (lane%LPR)*8 the col chunk.
template<int F>
__global__ void k_node(const int* __restrict__ off, const int* __restrict__ csr_src,
                       const float* __restrict__ we, const __half* __restrict__ h,
                       const float* __restrict__ bias, __half* __restrict__ outh, int N){
  constexpr int LPR = F / 8;
  constexpr int EPW = 64 / LPR;
  int lane = threadIdx.x & (WAVE - 1);
  int wid = (int)((blockIdx.x * blockDim.x + threadIdx.x) >> 6);
  int node = __builtin_amdgcn_readfirstlane(wid);
  if (node >= N) return;
  int o0 = off[node], o1 = off[node + 1];
  int q = lane / LPR;
  int cbase = (lane % LPR) * 8;

  float acc[8];
  #pragma unroll
  for (int i = 0; i < 8; ++i) acc[i] = 0.f;
  float wsum = 0.f;

  for (int jj = o0; jj < o1; jj += 2 * EPW){
    #pragma unroll
    for (int half = 0; half < 2; ++half){
      int j = jj + half * EPW + q;
      bool ok = j < o1;
      int jc = ok ? j : o0;
      int s = csr_src[jc];
      float w = ok ? we[jc] : 0.f;
      f16x8 hv = *(const f16x8*)(h + (size_t)s * F + cbase);
      wsum += w;
      #pragma unroll
      for (int i = 0; i < 8; ++i) acc[i] += w * (float)hv[i];
    }
  }

  // reduce across edge groups (lanes sharing lane%LPR)
  #pragma unroll
  for (int m = LPR; m < 64; m <<= 1){
    #pragma unroll
    for (int i = 0; i < 8; ++i) acc[i] += __shfl_xor(acc[i], m);
    wsum += __shfl_xor(wsum, m);
  }

  if (q == 0){
    float inv = 1.f / (wsum + 1e-16f);
    f16x8 o;
    #pragma unroll
    for (int i = 0; i < 8; ++i){
      float v = fmaxf(acc[i] * inv + bias[cbase + i], 0.f);
      o[i] = (_Float16)v;
    }
    *(f16x8*)(outh + (size_t)node * F + cbase) = o;
  }
}

// ---------------- pooling (batch sorted): strip reduction, few atomics ----------------
__global__ void k_pool(const __half* __restrict__ h, const int* __restrict__ batch,
                       float* __restrict__ pool, int* __restrict__ cnt, int N, int strip){
  int f = threadIdx.x;  // 0..127
  int n0 = blockIdx.x * strip;
  if (n0 >= N) return;
  int n1 = min(n0 + strip, N);
  int g = batch[n0];
  float acc = 0.f;
  int c = 0;
  for (int n = n0; n < n1; ++n){
    int gn = batch[n];
    if (gn != g){
      atomicAdd(&pool[g * F2 + f], acc);
      if (f == 0) atomicAdd(&cnt[g], c);
      acc = 0.f; c = 0; g = gn;
    }
    acc += __half2float(h[(size_t)n * F2 + f]);
    c++;
  }
  atomicAdd(&pool[g * F2 + f], acc);
  if (f == 0) atomicAdd(&cnt[g], c);
}

// ---------------- final FC ----------------
__global__ void k_fc(const float* __restrict__ pool, const int* __restrict__ cnt,
                     const float* __restrict__ Wfc, const float* __restrict__ bfc,
                     float* __restrict__ out){
  int g = blockIdx.x, o = threadIdx.x;  // 64 x 64
  __shared__ float p[F2];
  float invc = 1.f / fmaxf((float)cnt[g], 1.f);
  for (int k = threadIdx.x; k < F2; k += 64) p[k] = pool[g * F2 + k] * invc;
  __syncthreads();
  float acc = bfc[o];
  for (int k = 0; k < F2; ++k) acc += p[k] * Wfc[k * 64 + o];
  out[g * 64 + o] = acc;
}

extern "C" void kernel_launch(void* const* d_in, const int* in_sizes, int n_in,
                              void* d_out, int out_size, void* d_ws, size_t ws_size,
                              hipStream_t stream){
  const float* x    = (const float*)d_in[0];
  const int*   edge = (const int*)d_in[1];
  const int*   batch= (const int*)d_in[2];
  const float* W1   = (const float*)d_in[3];
  const float* av_s1= (const float*)d_in[4];
  const float* av_d1= (const float*)d_in[5];
  const float* b1   = (const float*)d_in[6];
  const float* W2   = (const float*)d_in[7];
  const float* av_s2= (const float*)d_in[8];
  const float* av_d2= (const float*)d_in[9];
  const float* b2   = (const float*)d_in[10];
  const float* Wfc  = (const float*)d_in[11];
  const float* bfc  = (const float*)d_in[12];
  float* out = (float*)d_out;

  const int N  = in_sizes[2];
  const int E  = in_sizes[1] / 2;
  const int Et = E + N;
  const int NB = (N + 255) >> 8;
  const int* src = edge;
  const int* dst = edge + E;

  char* p = (char*)d_ws;
  auto alloc = [&](size_t bytes)->void*{
    void* r = (void*)p;
    p += (bytes + 255) & ~(size_t)255;
    return r;
  };
  __half* h1  = (__half*)alloc((size_t)N * F1 * 2);
  __half* h1r = (__half*)alloc((size_t)N * F1 * 2);
  __half* h2  = (__half*)alloc((size_t)N * F2 * 2);
  __half* h2r = (__half*)alloc((size_t)N * F2 * 2);
  float* as1  = (float*)alloc((size_t)N * 4);
  float* ad1  = (float*)alloc((size_t)N * 4);
  float* as2  = (float*)alloc((size_t)N * 4);
  float* ad2  = (float*)alloc((size_t)N * 4);
  float* pool = (float*)alloc((size_t)NG * F2 * 4);
  float* we   = (float*)alloc((size_t)Et * 4);
  int* off    = (int*)alloc((size_t)(N + 1) * 4);
  int* csr_src= (int*)alloc((size_t)Et * 4);
  int* dst_arr= (int*)alloc((size_t)Et * 4);
  int* tmp    = (int*)alloc((size_t)Et * 4);
  int* cnt1   = (int*)alloc((size_t)256 * NBLK1 * 4);
  int* btot   = (int*)alloc((size_t)256 * 4);
  int* bbase  = (int*)alloc((size_t)257 * 4);
  int* cnt    = (int*)alloc((size_t)NG * 4);

  hipMemsetAsync(pool, 0, (size_t)NG * F2 * 4, stream);
  hipMemsetAsync(cnt, 0, (size_t)NG * 4, stream);

  // CSR build (no global atomics)
  int chunk = (Et + NBLK1 - 1) / NBLK1;
  k_hist<<<NBLK1, 256, 0, stream>>>(src, dst, E, N, NB, chunk, cnt1);
  k_colscan<<<NB, 256, 0, stream>>>(cnt1, btot);
  k_bucketscan<<<1, 256, 0, stream>>>(btot, NB, Et, bbase, off, N);
  k_scatter1<<<NBLK1, 256, 0, stream>>>(src, dst, E, N, NB, chunk, cnt1, bbase, tmp);
  k_sort2<<<NB, 256, 0, stream>>>(tmp, bbase, N, off, csr_src, dst_arr);

  int gemm_blocks = (N + 127) / 128;
  int node_blocks = (N + 3) / 4;   // 4 waves (nodes) per 256-thread block
  int wblocks = 2048;

  // layer 1
  k_gemm_mfma<D_IN, F1, true><<<gemm_blocks, 256, 0, stream>>>(x, W1, av_s1, av_d1,
                                                               h1, as1, ad1, N);
  k_weight<<<wblocks, 256, 0, stream>>>(csr_src, dst_arr, as1, ad1, we, Et);
  k_node<F1><<<node_blocks, 256, 0, stream>>>(off, csr_src, we, h1, b1, h1r, N);

  // layer 2
  k_gemm_mfma<F1, F2, false><<<gemm_blocks, 256, 0, stream>>>(h1r, W2, av_s2, av_d2,
                                                              h2, as2, ad2, N);
  k_weight<<<wblocks, 256, 0, stream>>>(csr_src, dst_arr, as2, ad2, we, Et);
  k_node<F2><<<node_blocks, 256, 0, stream>>>(off, csr_src, we, h2, b2, h2r, N);

  // pooling + FC
  int strip = 128;
  int pool_blocks = (N + strip - 1) / strip;
  k_pool<<<pool_blocks, F2, 0, stream>>>(h2r, batch, pool, cnt, N, strip);
  k_fc<<<NG, 64, 0, stream>>>(pool, cnt, Wfc, bfc, out);
}

// Round 9
// 223.653 us; speedup vs baseline: 1.0508x; 1.0336x over previous
//
#include <hip/hip_runtime.h>
#include <hip/hip_fp16.h>

#define WAVE 64

constexpr int D_IN = 128;
constexpr int F1 = 64;
constexpr int F2 = 128;
constexpr int NG = 64;
constexpr float NEG = 0.2f;
constexpr int NBLK1 = 512;       // level-1 binning blocks

using f16x8 = __attribute__((ext_vector_type(8))) _Float16;
using f32x4 = __attribute__((ext_vector_type(4))) float;

__device__ __forceinline__ float lrelu(float x){ return x > 0.f ? x : NEG * x; }

// ================= CSR build: two-level LDS-binned counting sort =================
__global__ void k_hist(const int* __restrict__ src, const int* __restrict__ dst,
                       int E, int N, int NB, int chunk, int* __restrict__ cnt1){
  __shared__ int hist[256];
  int b = blockIdx.x;
  for (int t = threadIdx.x; t < NB; t += blockDim.x) hist[t] = 0;
  __syncthreads();
  int Et = E + N;
  int s0 = b * chunk, s1 = min(s0 + chunk, Et);
  for (int i = s0 + (int)threadIdx.x; i < s1; i += (int)blockDim.x){
    int d = (i < E) ? dst[i] : (i - E);
    atomicAdd(&hist[d >> 8], 1);
  }
  __syncthreads();
  for (int t = threadIdx.x; t < NB; t += blockDim.x) cnt1[t * NBLK1 + b] = hist[t];
}

__global__ void k_colscan(int* __restrict__ cnt1, int* __restrict__ btot){
  __shared__ int lds[256];
  int b = blockIdx.x;
  int t = threadIdx.x;
  int v0 = cnt1[b * NBLK1 + 2 * t], v1 = cnt1[b * NBLK1 + 2 * t + 1];
  int p = v0 + v1;
  lds[t] = p; __syncthreads();
  #pragma unroll
  for (int s = 1; s < 256; s <<= 1){
    int u = (t >= s) ? lds[t - s] : 0;
    __syncthreads(); lds[t] += u; __syncthreads();
  }
  int epre = lds[t] - p;
  cnt1[b * NBLK1 + 2 * t] = epre;
  cnt1[b * NBLK1 + 2 * t + 1] = epre + v0;
  if (t == 255) btot[b] = lds[255];
}

__global__ void k_bucketscan(const int* __restrict__ btot, int NB, int Et,
                             int* __restrict__ bbase, int* __restrict__ off, int N){
  __shared__ int lds[256];
  int t = threadIdx.x;
  int v = (t < NB) ? btot[t] : 0;
  lds[t] = v; __syncthreads();
  #pragma unroll
  for (int s = 1; s < 256; s <<= 1){
    int u = (t >= s) ? lds[t - s] : 0;
    __syncthreads(); lds[t] += u; __syncthreads();
  }
  if (t < NB) bbase[t] = lds[t] - v;
  if (t == 0){ bbase[NB] = Et; off[N] = Et; }
}

__global__ void k_scatter1(const int* __restrict__ src, const int* __restrict__ dst,
                           int E, int N, int NB, int chunk,
                           const int* __restrict__ cnt1, const int* __restrict__ bbase,
                           int* __restrict__ tmp){
  __shared__ int cur[256];
  int b = blockIdx.x;
  for (int t = threadIdx.x; t < NB; t += blockDim.x) cur[t] = bbase[t] + cnt1[t * NBLK1 + b];
  __syncthreads();
  int Et = E + N;
  int s0 = b * chunk, s1 = min(s0 + chunk, Et);
  for (int i = s0 + (int)threadIdx.x; i < s1; i += (int)blockDim.x){
    int s, d;
    if (i < E){ s = src[i]; d = dst[i]; } else { s = d = i - E; }
    int bk = d >> 8;
    int p = atomicAdd(&cur[bk], 1);
    tmp[p] = (s << 8) | (d & 255);
  }
}

__global__ void k_sort2(const int* __restrict__ tmp, const int* __restrict__ bbase,
                        int N, int* __restrict__ off, int* __restrict__ csr_src){
  __shared__ int hist[256];
  __shared__ int pre[256];
  int b = blockIdx.x;
  int t = threadIdx.x;
  hist[t] = 0;
  __syncthreads();
  int g0 = bbase[b], g1 = bbase[b + 1];
  for (int i = g0 + t; i < g1; i += 256) atomicAdd(&hist[tmp[i] & 255], 1);
  __syncthreads();
  int v = hist[t];
  pre[t] = v; __syncthreads();
  #pragma unroll
  for (int s = 1; s < 256; s <<= 1){
    int u = (t >= s) ? pre[t - s] : 0;
    __syncthreads(); pre[t] += u; __syncthreads();
  }
  int ex = pre[t] - v;
  int node = (b << 8) + t;
  if (node < N) off[node] = g0 + ex;
  hist[t] = ex;
  __syncthreads();
  for (int i = g0 + t; i < g1; i += 256){
    int e = tmp[i];
    int p = g0 + atomicAdd(&hist[e & 255], 1);
    csr_src[p] = e >> 8;
  }
}

// ============ MFMA GEMM: Ch[M,FO](fp16) = A[M,FI] @ W[FI,FO]; plus as/ad dots ============
template<int FI, int FO, bool AF32>
__global__ void k_gemm_mfma(const void* __restrict__ Av, const float* __restrict__ W,
                            const float* __restrict__ avs, const float* __restrict__ avd,
                            __half* __restrict__ Ch, float* __restrict__ as_, float* __restrict__ ad_,
                            int M){
  constexpr int NT = FO / 16;
  constexpr int KT = FI / 32;
  constexpr int MT = 2;
  __shared__ _Float16 blds[NT * KT * 64 * 8];

  int tid = threadIdx.x;
  for (int fl = tid; fl < NT * KT * 64; fl += 256){
    int l = fl & 63, kt = (fl >> 6) % KT, nt = fl / (64 * KT);
    int n = nt * 16 + (l & 15), kb = kt * 32 + (l >> 4) * 8;
    f16x8 v;
    #pragma unroll
    for (int i = 0; i < 8; ++i) v[i] = (_Float16)W[(size_t)(kb + i) * FO + n];
    *(f16x8*)&blds[(size_t)fl * 8] = v;
  }
  __syncthreads();

  int lane = tid & 63, wave = tid >> 6;
  int rbase = lane & 15, kgrp = lane >> 4;
  int r0 = blockIdx.x * (MT * 16 * 4) + wave * (MT * 16);

  f32x4 c[MT][NT];
  #pragma unroll
  for (int mt = 0; mt < MT; ++mt)
    #pragma unroll
    for (int nt = 0; nt < NT; ++nt)
      c[mt][nt] = (f32x4){0.f, 0.f, 0.f, 0.f};

  for (int kt = 0; kt < KT; ++kt){
    f16x8 a[MT];
    #pragma unroll
    for (int mt = 0; mt < MT; ++mt){
      int arow = min(r0 + mt * 16 + rbase, M - 1);
      if (AF32){
        const float* ap = (const float*)Av + (size_t)arow * FI + kt * 32 + kgrp * 8;
        float4 p0 = *(const float4*)ap;
        float4 p1 = *(const float4*)(ap + 4);
        a[mt][0] = (_Float16)p0.x; a[mt][1] = (_Float16)p0.y;
        a[mt][2] = (_Float16)p0.z; a[mt][3] = (_Float16)p0.w;
        a[mt][4] = (_Float16)p1.x; a[mt][5] = (_Float16)p1.y;
        a[mt][6] = (_Float16)p1.z; a[mt][7] = (_Float16)p1.w;
      } else {
        const __half* ap = (const __half*)Av + (size_t)arow * FI + kt * 32 + kgrp * 8;
        a[mt] = *(const f16x8*)ap;
      }
    }
    #pragma unroll
    for (int nt = 0; nt < NT; ++nt){
      f16x8 b = *(f16x8*)&blds[(size_t)((nt * KT + kt) * 64 + lane) * 8];
      #pragma unroll
      for (int mt = 0; mt < MT; ++mt)
        c[mt][nt] = __builtin_amdgcn_mfma_f32_16x16x32_f16(a[mt], b, c[mt][nt], 0, 0, 0);
    }
  }

  float avs_v[NT], avd_v[NT];
  #pragma unroll
  for (int nt = 0; nt < NT; ++nt){
    avs_v[nt] = avs[nt * 16 + rbase];
    avd_v[nt] = avd[nt * 16 + rbase];
  }
  #pragma unroll
  for (int mt = 0; mt < MT; ++mt){
    #pragma unroll
    for (int i = 0; i < 4; ++i){
      int grow = r0 + mt * 16 + kgrp * 4 + i;
      bool ok = grow < M;
      float s1 = 0.f, s2 = 0.f;
      #pragma unroll
      for (int nt = 0; nt < NT; ++nt){
        float d = c[mt][nt][i];
        if (ok) Ch[(size_t)grow * FO + nt * 16 + rbase] = __float2half(d);
        s1 += d * avs_v[nt];
        s2 += d * avd_v[nt];
      }
      #pragma unroll
      for (int msk = 1; msk <= 8; msk <<= 1){
        s1 += __shfl_xor(s1, msk);
        s2 += __shfl_xor(s2, msk);
      }
      if (ok && rbase == 0){ as_[grow] = s1; ad_[grow] = s2; }
    }
  }
}

// -------- aggregation: grouped gather + fused in-group softmax weight --------
// LPR = F/8 lanes cover one row; EPW = 64/LPR edges per wave-instruction.
// lane q = lane/LPR is the edge slot, cbase = (lane%LPR)*8 the col chunk.
// Weight computed redundantly by the LPR lanes of a group (broadcast as_ load).
template<int F>
__global__ void k_node(const int* __restrict__ off, const int* __restrict__ csr_src,
                       const float* __restrict__ as_, const float* __restrict__ ad_,
                       const __half* __restrict__ h, const float* __restrict__ bias,
                       __half* __restrict__ outh, int N){
  constexpr int LPR = F / 8;
  constexpr int EPW = 64 / LPR;
  int lane = threadIdx.x & (WAVE - 1);
  int wid = (int)((blockIdx.x * blockDim.x + threadIdx.x) >> 6);
  int node = __builtin_amdgcn_readfirstlane(wid);
  if (node >= N) return;
  int o0 = off[node], o1 = off[node + 1];
  float add = ad_[node];
  int q = lane / LPR;
  int cbase = (lane % LPR) * 8;

  float acc[8];
  #pragma unroll
  for (int i = 0; i < 8; ++i) acc[i] = 0.f;
  float wsum = 0.f;

  for (int jj = o0; jj < o1; jj += 2 * EPW){
    #pragma unroll
    for (int half = 0; half < 2; ++half){
      int j = jj + half * EPW + q;
      bool ok = j < o1;
      int jc = ok ? j : o0;
      int s = csr_src[jc];
      float e = as_[s] + add;
      float w = ok ? __expf(lrelu(e)) : 0.f;
      f16x8 hv = *(const f16x8*)(h + (size_t)s * F + cbase);
      wsum += w;
      #pragma unroll
      for (int i = 0; i < 8; ++i) acc[i] += w * (float)hv[i];
    }
  }

  // reduce across edge groups (lanes sharing lane%LPR)
  #pragma unroll
  for (int m = LPR; m < 64; m <<= 1){
    #pragma unroll
    for (int i = 0; i < 8; ++i) acc[i] += __shfl_xor(acc[i], m);
    wsum += __shfl_xor(wsum, m);
  }

  if (q == 0){
    float inv = 1.f / (wsum + 1e-16f);
    f16x8 o;
    #pragma unroll
    for (int i = 0; i < 8; ++i){
      float v = fmaxf(acc[i] * inv + bias[cbase + i], 0.f);
      o[i] = (_Float16)v;
    }
    *(f16x8*)(outh + (size_t)node * F + cbase) = o;
  }
}

// ---------------- pooling (batch sorted): strip reduction, few atomics ----------------
__global__ void k_pool(const __half* __restrict__ h, const int* __restrict__ batch,
                       float* __restrict__ pool, int* __restrict__ cnt, int N, int strip){
  int f = threadIdx.x;  // 0..127
  int n0 = blockIdx.x * strip;
  if (n0 >= N) return;
  int n1 = min(n0 + strip, N);
  int g = batch[n0];
  float acc = 0.f;
  int c = 0;
  for (int n = n0; n < n1; ++n){
    int gn = batch[n];
    if (gn != g){
      atomicAdd(&pool[g * F2 + f], acc);
      if (f == 0) atomicAdd(&cnt[g], c);
      acc = 0.f; c = 0; g = gn;
    }
    acc += __half2float(h[(size_t)n * F2 + f]);
    c++;
  }
  atomicAdd(&pool[g * F2 + f], acc);
  if (f == 0) atomicAdd(&cnt[g], c);
}

// ---------------- final FC ----------------
__global__ void k_fc(const float* __restrict__ pool, const int* __restrict__ cnt,
                     const float* __restrict__ Wfc, const float* __restrict__ bfc,
                     float* __restrict__ out){
  int g = blockIdx.x, o = threadIdx.x;  // 64 x 64
  __shared__ float p[F2];
  float invc = 1.f / fmaxf((float)cnt[g], 1.f);
  for (int k = threadIdx.x; k < F2; k += 64) p[k] = pool[g * F2 + k] * invc;
  __syncthreads();
  float acc = bfc[o];
  for (int k = 0; k < F2; ++k) acc += p[k] * Wfc[k * 64 + o];
  out[g * 64 + o] = acc;
}

extern "C" void kernel_launch(void* const* d_in, const int* in_sizes, int n_in,
                              void* d_out, int out_size, void* d_ws, size_t ws_size,
                              hipStream_t stream){
  const float* x    = (const float*)d_in[0];
  const int*   edge = (const int*)d_in[1];
  const int*   batch= (const int*)d_in[2];
  const float* W1   = (const float*)d_in[3];
  const float* av_s1= (const float*)d_in[4];
  const float* av_d1= (const float*)d_in[5];
  const float* b1   = (const float*)d_in[6];
  const float* W2   = (const float*)d_in[7];
  const float* av_s2= (const float*)d_in[8];
  const float* av_d2= (const float*)d_in[9];
  const float* b2   = (const float*)d_in[10];
  const float* Wfc  = (const float*)d_in[11];
  const float* bfc  = (const float*)d_in[12];
  float* out = (float*)d_out;

  const int N  = in_sizes[2];
  const int E  = in_sizes[1] / 2;
  const int Et = E + N;
  const int NB = (N + 255) >> 8;
  const int* src = edge;
  const int* dst = edge + E;

  char* p = (char*)d_ws;
  auto alloc = [&](size_t bytes)->void*{
    void* r = (void*)p;
    p += (bytes + 255) & ~(size_t)255;
    return r;
  };
  __half* h1  = (__half*)alloc((size_t)N * F1 * 2);
  __half* h1r = (__half*)alloc((size_t)N * F1 * 2);
  __half* h2  = (__half*)alloc((size_t)N * F2 * 2);
  __half* h2r = (__half*)alloc((size_t)N * F2 * 2);
  float* as1  = (float*)alloc((size_t)N * 4);
  float* ad1  = (float*)alloc((size_t)N * 4);
  float* as2  = (float*)alloc((size_t)N * 4);
  float* ad2  = (float*)alloc((size_t)N * 4);
  float* pool = (float*)alloc((size_t)NG * F2 * 4);
  int* off    = (int*)alloc((size_t)(N + 1) * 4);
  int* csr_src= (int*)alloc((size_t)Et * 4);
  int* tmp    = (int*)alloc((size_t)Et * 4);
  int* cnt1   = (int*)alloc((size_t)256 * NBLK1 * 4);
  int* btot   = (int*)alloc((size_t)256 * 4);
  int* bbase  = (int*)alloc((size_t)257 * 4);
  int* cnt    = (int*)alloc((size_t)NG * 4);

  hipMemsetAsync(pool, 0, (size_t)NG * F2 * 4, stream);
  hipMemsetAsync(cnt, 0, (size_t)NG * 4, stream);

  // CSR build (no global atomics)
  int chunk = (Et + NBLK1 - 1) / NBLK1;
  k_hist<<<NBLK1, 256, 0, stream>>>(src, dst, E, N, NB, chunk, cnt1);
  k_colscan<<<NB, 256, 0, stream>>>(cnt1, btot);
  k_bucketscan<<<1, 256, 0, stream>>>(btot, NB, Et, bbase, off, N);
  k_scatter1<<<NBLK1, 256, 0, stream>>>(src, dst, E, N, NB, chunk, cnt1, bbase, tmp);
  k_sort2<<<NB, 256, 0, stream>>>(tmp, bbase, N, off, csr_src);

  int gemm_blocks = (N + 127) / 128;
  int node_blocks = (N + 3) / 4;   // 4 waves (nodes) per 256-thread block

  // layer 1
  k_gemm_mfma<D_IN, F1, true><<<gemm_blocks, 256, 0, stream>>>(x, W1, av_s1, av_d1,
                                                               h1, as1, ad1, N);
  k_node<F1><<<node_blocks, 256, 0, stream>>>(off, csr_src, as1, ad1, h1, b1, h1r, N);

  // layer 2
  k_gemm_mfma<F1, F2, false><<<gemm_blocks, 256, 0, stream>>>(h1r, W2, av_s2, av_d2,
                                                              h2, as2, ad2, N);
  k_node<F2><<<node_blocks, 256, 0, stream>>>(off, csr_src, as2, ad2, h2, b2, h2r, N);

  // pooling + FC
  int strip = 128;
  int pool_blocks = (N + strip - 1) / strip;
  k_pool<<<pool_blocks, F2, 0, stream>>>(h2r, batch, pool, cnt, N, strip);
  k_fc<<<NG, 64, 0, stream>>>(pool, cnt, Wfc, bfc, out);
}

// Round 10
// 197.158 us; speedup vs baseline: 1.1920x; 1.1344x over previous
//
#include <hip/hip_runtime.h>
#include <hip/hip_fp16.h>

#define WAVE 64

constexpr int D_IN = 128;
constexpr int F1 = 64;
constexpr int F2 = 128;
constexpr int NG = 64;
constexpr float NEG = 0.2f;
constexpr int NBLK1 = 512;       // level-1 binning blocks

using f16x8 = __attribute__((ext_vector_type(8))) _Float16;
using f32x4 = __attribute__((ext_vector_type(4))) float;

__device__ __forceinline__ float lrelu(float x){ return x > 0.f ? x : NEG * x; }

// ================= CSR build: two-level LDS-binned counting sort =================
__global__ void k_hist(const int* __restrict__ src, const int* __restrict__ dst,
                       int E, int N, int NB, int chunk, int* __restrict__ cnt1){
  __shared__ int hist[256];
  int b = blockIdx.x;
  for (int t = threadIdx.x; t < NB; t += blockDim.x) hist[t] = 0;
  __syncthreads();
  int Et = E + N;
  int s0 = b * chunk, s1 = min(s0 + chunk, Et);
  for (int i = s0 + (int)threadIdx.x; i < s1; i += (int)blockDim.x){
    int d = (i < E) ? dst[i] : (i - E);
    atomicAdd(&hist[d >> 8], 1);
  }
  __syncthreads();
  for (int t = threadIdx.x; t < NB; t += blockDim.x) cnt1[t * NBLK1 + b] = hist[t];
}

__global__ void k_colscan(int* __restrict__ cnt1, int* __restrict__ btot){
  __shared__ int lds[256];
  int b = blockIdx.x;
  int t = threadIdx.x;
  int v0 = cnt1[b * NBLK1 + 2 * t], v1 = cnt1[b * NBLK1 + 2 * t + 1];
  int p = v0 + v1;
  lds[t] = p; __syncthreads();
  #pragma unroll
  for (int s = 1; s < 256; s <<= 1){
    int u = (t >= s) ? lds[t - s] : 0;
    __syncthreads(); lds[t] += u; __syncthreads();
  }
  int epre = lds[t] - p;
  cnt1[b * NBLK1 + 2 * t] = epre;
  cnt1[b * NBLK1 + 2 * t + 1] = epre + v0;
  if (t == 255) btot[b] = lds[255];
}

__global__ void k_bucketscan(const int* __restrict__ btot, int NB, int Et,
                             int* __restrict__ bbase, int* __restrict__ off, int N){
  __shared__ int lds[256];
  int t = threadIdx.x;
  int v = (t < NB) ? btot[t] : 0;
  lds[t] = v; __syncthreads();
  #pragma unroll
  for (int s = 1; s < 256; s <<= 1){
    int u = (t >= s) ? lds[t - s] : 0;
    __syncthreads(); lds[t] += u; __syncthreads();
  }
  if (t < NB) bbase[t] = lds[t] - v;
  if (t == 0){ bbase[NB] = Et; off[N] = Et; }
}

__global__ void k_scatter1(const int* __restrict__ src, const int* __restrict__ dst,
                           int E, int N, int NB, int chunk,
                           const int* __restrict__ cnt1, const int* __restrict__ bbase,
                           int* __restrict__ tmp){
  __shared__ int cur[256];
  int b = blockIdx.x;
  for (int t = threadIdx.x; t < NB; t += blockDim.x) cur[t] = bbase[t] + cnt1[t * NBLK1 + b];
  __syncthreads();
  int Et = E + N;
  int s0 = b * chunk, s1 = min(s0 + chunk, Et);
  for (int i = s0 + (int)threadIdx.x; i < s1; i += (int)blockDim.x){
    int s, d;
    if (i < E){ s = src[i]; d = dst[i]; } else { s = d = i - E; }
    int bk = d >> 8;
    int p = atomicAdd(&cur[bk], 1);
    tmp[p] = (s << 8) | (d & 255);
  }
}

__global__ void k_sort2(const int* __restrict__ tmp, const int* __restrict__ bbase,
                        int N, int* __restrict__ off, int* __restrict__ csr_src){
  __shared__ int hist[256];
  __shared__ int pre[256];
  int b = blockIdx.x;
  int t = threadIdx.x;
  hist[t] = 0;
  __syncthreads();
  int g0 = bbase[b], g1 = bbase[b + 1];
  for (int i = g0 + t; i < g1; i += 256) atomicAdd(&hist[tmp[i] & 255], 1);
  __syncthreads();
  int v = hist[t];
  pre[t] = v; __syncthreads();
  #pragma unroll
  for (int s = 1; s < 256; s <<= 1){
    int u = (t >= s) ? pre[t - s] : 0;
    __syncthreads(); pre[t] += u; __syncthreads();
  }
  int ex = pre[t] - v;
  int node = (b << 8) + t;
  if (node < N) off[node] = g0 + ex;
  hist[t] = ex;
  __syncthreads();
  for (int i = g0 + t; i < g1; i += 256){
    int e = tmp[i];
    int p = g0 + atomicAdd(&hist[e & 255], 1);
    csr_src[p] = e >> 8;
  }
}

// ============ MFMA GEMM: Ch[M,FO](fp16) = A[M,FI] @ W[FI,FO]; plus as/ad dots ============
template<int FI, int FO, bool AF32>
__global__ void k_gemm_mfma(const void* __restrict__ Av, const float* __restrict__ W,
                            const float* __restrict__ avs, const float* __restrict__ avd,
                            __half* __restrict__ Ch, float* __restrict__ as_, float* __restrict__ ad_,
                            int M){
  constexpr int NT = FO / 16;
  constexpr int KT = FI / 32;
  constexpr int MT = 2;
  __shared__ _Float16 blds[NT * KT * 64 * 8];

  int tid = threadIdx.x;
  for (int fl = tid; fl < NT * KT * 64; fl += 256){
    int l = fl & 63, kt = (fl >> 6) % KT, nt = fl / (64 * KT);
    int n = nt * 16 + (l & 15), kb = kt * 32 + (l >> 4) * 8;
    f16x8 v;
    #pragma unroll
    for (int i = 0; i < 8; ++i) v[i] = (_Float16)W[(size_t)(kb + i) * FO + n];
    *(f16x8*)&blds[(size_t)fl * 8] = v;
  }
  __syncthreads();

  int lane = tid & 63, wave = tid >> 6;
  int rbase = lane & 15, kgrp = lane >> 4;
  int r0 = blockIdx.x * (MT * 16 * 4) + wave * (MT * 16);

  f32x4 c[MT][NT];
  #pragma unroll
  for (int mt = 0; mt < MT; ++mt)
    #pragma unroll
    for (int nt = 0; nt < NT; ++nt)
      c[mt][nt] = (f32x4){0.f, 0.f, 0.f, 0.f};

  for (int kt = 0; kt < KT; ++kt){
    f16x8 a[MT];
    #pragma unroll
    for (int mt = 0; mt < MT; ++mt){
      int arow = min(r0 + mt * 16 + rbase, M - 1);
      if (AF32){
        const float* ap = (const float*)Av + (size_t)arow * FI + kt * 32 + kgrp * 8;
        float4 p0 = *(const float4*)ap;
        float4 p1 = *(const float4*)(ap + 4);
        a[mt][0] = (_Float16)p0.x; a[mt][1] = (_Float16)p0.y;
        a[mt][2] = (_Float16)p0.z; a[mt][3] = (_Float16)p0.w;
        a[mt][4] = (_Float16)p1.x; a[mt][5] = (_Float16)p1.y;
        a[mt][6] = (_Float16)p1.z; a[mt][7] = (_Float16)p1.w;
      } else {
        const __half* ap = (const __half*)Av + (size_t)arow * FI + kt * 32 + kgrp * 8;
        a[mt] = *(const f16x8*)ap;
      }
    }
    #pragma unroll
    for (int nt = 0; nt < NT; ++nt){
      f16x8 b = *(f16x8*)&blds[(size_t)((nt * KT + kt) * 64 + lane) * 8];
      #pragma unroll
      for (int mt = 0; mt < MT; ++mt)
        c[mt][nt] = __builtin_amdgcn_mfma_f32_16x16x32_f16(a[mt], b, c[mt][nt], 0, 0, 0);
    }
  }

  float avs_v[NT], avd_v[NT];
  #pragma unroll
  for (int nt = 0; nt < NT; ++nt){
    avs_v[nt] = avs[nt * 16 + rbase];
    avd_v[nt] = avd[nt * 16 + rbase];
  }
  #pragma unroll
  for (int mt = 0; mt < MT; ++mt){
    #pragma unroll
    for (int i = 0; i < 4; ++i){
      int grow = r0 + mt * 16 + kgrp * 4 + i;
      bool ok = grow < M;
      float s1 = 0.f, s2 = 0.f;
      #pragma unroll
      for (int nt = 0; nt < NT; ++nt){
        float d = c[mt][nt][i];
        if (ok) Ch[(size_t)grow * FO + nt * 16 + rbase] = __float2half(d);
        s1 += d * avs_v[nt];
        s2 += d * avd_v[nt];
      }
      #pragma unroll
      for (int msk = 1; msk <= 8; msk <<= 1){
        s1 += __shfl_xor(s1, msk);
        s2 += __shfl_xor(s2, msk);
      }
      if (ok && rbase == 0){ as_[grow] = s1; ad_[grow] = s2; }
    }
  }
}

// -------- aggregation: grouped gather + fused weight, 4-deep software pipeline --------
// LPR = F/8 lanes cover one row; EPW = 64/LPR edges per wave-instruction.
// lane q = lane/LPR is the edge slot, cbase = (lane%LPR)*8 the col chunk.
// U=4 independent edge-groups staged per iteration for MLP.
template<int F>
__global__ void k_node(const int* __restrict__ off, const int* __restrict__ csr_src,
                       const float* __restrict__ as_, const float* __restrict__ ad_,
                       const __half* __restrict__ h, const float* __restrict__ bias,
                       __half* __restrict__ outh, int N){
  constexpr int LPR = F / 8;
  constexpr int EPW = 64 / LPR;
  constexpr int U = 4;
  int lane = threadIdx.x & (WAVE - 1);
  int wid = (int)((blockIdx.x * blockDim.x + threadIdx.x) >> 6);
  int node = __builtin_amdgcn_readfirstlane(wid);
  if (node >= N) return;
  int o0 = off[node], o1 = off[node + 1];
  float add = ad_[node];
  int q = lane / LPR;
  int cbase = (lane % LPR) * 8;

  float acc[8];
  #pragma unroll
  for (int i = 0; i < 8; ++i) acc[i] = 0.f;
  float wsum = 0.f;

  for (int jj = o0; jj < o1; jj += U * EPW){
    // stage 1: all indices
    int s[U]; bool okv[U];
    #pragma unroll
    for (int u = 0; u < U; ++u){
      int j = jj + u * EPW + q;
      okv[u] = j < o1;
      s[u] = csr_src[okv[u] ? j : o0];
    }
    // stage 2: issue all as_ gathers and all h row gathers (independent chains)
    float araw[U];
    #pragma unroll
    for (int u = 0; u < U; ++u) araw[u] = as_[s[u]];
    f16x8 hv[U];
    #pragma unroll
    for (int u = 0; u < U; ++u) hv[u] = *(const f16x8*)(h + (size_t)s[u] * F + cbase);
    // stage 3: VALU
    #pragma unroll
    for (int u = 0; u < U; ++u){
      float w = okv[u] ? __expf(lrelu(araw[u] + add)) : 0.f;
      wsum += w;
      #pragma unroll
      for (int i = 0; i < 8; ++i) acc[i] += w * (float)hv[u][i];
    }
  }

  // reduce across edge groups (lanes sharing lane%LPR)
  #pragma unroll
  for (int m = LPR; m < 64; m <<= 1){
    #pragma unroll
    for (int i = 0; i < 8; ++i) acc[i] += __shfl_xor(acc[i], m);
    wsum += __shfl_xor(wsum, m);
  }

  if (q == 0){
    float inv = 1.f / (wsum + 1e-16f);
    f16x8 o;
    #pragma unroll
    for (int i = 0; i < 8; ++i){
      float v = fmaxf(acc[i] * inv + bias[cbase + i], 0.f);
      o[i] = (_Float16)v;
    }
    *(f16x8*)(outh + (size_t)node * F + cbase) = o;
  }
}

// ---------------- pooling (batch sorted): strip reduction, few atomics ----------------
__global__ void k_pool(const __half* __restrict__ h, const int* __restrict__ batch,
                       float* __restrict__ pool, int* __restrict__ cnt, int N, int strip){
  int f = threadIdx.x;  // 0..127
  int n0 = blockIdx.x * strip;
  if (n0 >= N) return;
  int n1 = min(n0 + strip, N);
  int g = batch[n0];
  float acc = 0.f;
  int c = 0;
  for (int n = n0; n < n1; ++n){
    int gn = batch[n];
    if (gn != g){
      atomicAdd(&pool[g * F2 + f], acc);
      if (f == 0) atomicAdd(&cnt[g], c);
      acc = 0.f; c = 0; g = gn;
    }
    acc += __half2float(h[(size_t)n * F2 + f]);
    c++;
  }
  atomicAdd(&pool[g * F2 + f], acc);
  if (f == 0) atomicAdd(&cnt[g], c);
}

// ---------------- final FC ----------------
__global__ void k_fc(const float* __restrict__ pool, const int* __restrict__ cnt,
                     const float* __restrict__ Wfc, const float* __restrict__ bfc,
                     float* __restrict__ out){
  int g = blockIdx.x, o = threadIdx.x;  // 64 x 64
  __shared__ float p[F2];
  float invc = 1.f / fmaxf((float)cnt[g], 1.f);
  for (int k = threadIdx.x; k < F2; k += 64) p[k] = pool[g * F2 + k] * invc;
  __syncthreads();
  float acc = bfc[o];
  for (int k = 0; k < F2; ++k) acc += p[k] * Wfc[k * 64 + o];
  out[g * 64 + o] = acc;
}

extern "C" void kernel_launch(void* const* d_in, const int* in_sizes, int n_in,
                              void* d_out, int out_size, void* d_ws, size_t ws_size,
                              hipStream_t stream){
  const float* x    = (const float*)d_in[0];
  const int*   edge = (const int*)d_in[1];
  const int*   batch= (const int*)d_in[2];
  const float* W1   = (const float*)d_in[3];
  const float* av_s1= (const float*)d_in[4];
  const float* av_d1= (const float*)d_in[5];
  const float* b1   = (const float*)d_in[6];
  const float* W2   = (const float*)d_in[7];
  const float* av_s2= (const float*)d_in[8];
  const float* av_d2= (const float*)d_in[9];
  const float* b2   = (const float*)d_in[10];
  const float* Wfc  = (const float*)d_in[11];
  const float* bfc  = (const float*)d_in[12];
  float* out = (float*)d_out;

  const int N  = in_sizes[2];
  const int E  = in_sizes[1] / 2;
  const int Et = E + N;
  const int NB = (N + 255) >> 8;
  const int* src = edge;
  const int* dst = edge + E;

  char* p = (char*)d_ws;
  auto alloc = [&](size_t bytes)->void*{
    void* r = (void*)p;
    p += (bytes + 255) & ~(size_t)255;
    return r;
  };
  __half* h1  = (__half*)alloc((size_t)N * F1 * 2);
  __half* h1r = (__half*)alloc((size_t)N * F1 * 2);
  __half* h2  = (__half*)alloc((size_t)N * F2 * 2);
  __half* h2r = (__half*)alloc((size_t)N * F2 * 2);
  float* as1  = (float*)alloc((size_t)N * 4);
  float* ad1  = (float*)alloc((size_t)N * 4);
  float* as2  = (float*)alloc((size_t)N * 4);
  float* ad2  = (float*)alloc((size_t)N * 4);
  float* pool = (float*)alloc((size_t)NG * F2 * 4);
  int* off    = (int*)alloc((size_t)(N + 1) * 4);
  int* csr_src= (int*)alloc((size_t)Et * 4);
  int* tmp    = (int*)alloc((size_t)Et * 4);
  int* cnt1   = (int*)alloc((size_t)256 * NBLK1 * 4);
  int* btot   = (int*)alloc((size_t)256 * 4);
  int* bbase  = (int*)alloc((size_t)257 * 4);
  int* cnt    = (int*)alloc((size_t)NG * 4);

  hipMemsetAsync(pool, 0, (size_t)NG * F2 * 4, stream);
  hipMemsetAsync(cnt, 0, (size_t)NG * 4, stream);

  // CSR build (no global atomics)
  int chunk = (Et + NBLK1 - 1) / NBLK1;
  k_hist<<<NBLK1, 256, 0, stream>>>(src, dst, E, N, NB, chunk, cnt1);
  k_colscan<<<NB, 256, 0, stream>>>(cnt1, btot);
  k_bucketscan<<<1, 256, 0, stream>>>(btot, NB, Et, bbase, off, N);
  k_scatter1<<<NBLK1, 256, 0, stream>>>(src, dst, E, N, NB, chunk, cnt1, bbase, tmp);
  k_sort2<<<NB, 256, 0, stream>>>(tmp, bbase, N, off, csr_src);

  int gemm_blocks = (N + 127) / 128;
  int node_blocks = (N + 3) / 4;   // 4 waves (nodes) per 256-thread block

  // layer 1
  k_gemm_mfma<D_IN, F1, true><<<gemm_blocks, 256, 0, stream>>>(x, W1, av_s1, av_d1,
                                                               h1, as1, ad1, N);
  k_node<F1><<<node_blocks, 256, 0, stream>>>(off, csr_src, as1, ad1, h1, b1, h1r, N);

  // layer 2
  k_gemm_mfma<F1, F2, false><<<gemm_blocks, 256, 0, stream>>>(h1r, W2, av_s2, av_d2,
                                                              h2, as2, ad2, N);
  k_node<F2><<<node_blocks, 256, 0, stream>>>(off, csr_src, as2, ad2, h2, b2, h2r, N);

  // pooling + FC
  int strip = 128;
  int pool_blocks = (N + strip - 1) / strip;
  k_pool<<<pool_blocks, F2, 0, stream>>>(h2r, batch, pool, cnt, N, strip);
  k_fc<<<NG, 64, 0, stream>>>(pool, cnt, Wfc, bfc, out);
}